// Round 8
// baseline (315.585 us; speedup 1.0000x reference)
//
#include <hip/hip_runtime.h>

typedef _Float16 h16x8 __attribute__((ext_vector_type(8)));
typedef _Float16 h16x4 __attribute__((ext_vector_type(4)));
typedef _Float16 h16x2 __attribute__((ext_vector_type(2)));
typedef float    f32x4 __attribute__((ext_vector_type(4)));

#define NDIM   12288
#define KDIM   4096
#define MDIM   256
#define N_TILE 48
#define NT     32      // K tiles of 128 (= GROUP_SIZE)

// Pre-pass: x f32 -> f16 (exact: x was originally fp16).
__global__ __launch_bounds__(256) void cvt_x_kernel(const float* __restrict__ x,
                                                    _Float16* __restrict__ xf) {
    int i = blockIdx.x * 256 + threadIdx.x;
    f32x4 v = *(const f32x4*)(x + (size_t)i * 4);
    h16x4 h;
    h[0] = (_Float16)v[0]; h[1] = (_Float16)v[1];
    h[2] = (_Float16)v[2]; h[3] = (_Float16)v[3];
    *(h16x4*)(xf + (size_t)i * 4) = h;
}

// 256 blocks x 1024 threads (16 waves). Block tile: 256m x 48n, full K.
// W fetched from HBM exactly once. Counted-waitcnt barriers (T4): W loads stay
// in flight across s_barrier; only lgkmcnt(0) drained per tile.
template<int USE_F16X>
__global__ __launch_bounds__(1024, 4) void qlin_kernel(
    const float*    __restrict__ xf32,   // [256][4096] fp32
    const _Float16* __restrict__ xf16,   // [256][4096] f16 (ws)
    const float*    __restrict__ scales, // [12288][32] fp32
    const float*    __restrict__ bias,   // [12288]     fp32
    const int*      __restrict__ wq,     // [12288][4096]
    float*          __restrict__ out)    // [256][12288] fp32
{
    __shared__ char  wl[2][N_TILE * 256];   // dequant f16 W, XOR-swizzled
    __shared__ float sc[N_TILE * 32];

    const int tid  = threadIdx.x;
    const int lane = tid & 63;
    const int wave = tid >> 6;              // 0..15
    const int n0   = blockIdx.x * N_TILE;

    for (int j = tid; j < N_TILE * 32; j += 1024)
        sc[j] = scales[(size_t)(n0 + (j >> 5)) * 32 + (j & 31)];

    // W staging: wave w stages rows {w, w+16, w+32}; one wave-inst = one full
    // 128-k row slice (64 x int2 = 512B contiguous). Scale wave-uniform.
    const int2* wb0 = (const int2*)wq + (size_t)(n0 + wave     ) * 2048 + lane;
    const int2* wb1 = (const int2*)wq + (size_t)(n0 + wave + 16) * 2048 + lane;
    const int2* wb2 = (const int2*)wq + (size_t)(n0 + wave + 32) * 2048 + lane;
    const int xors = (wave & 7) << 4;
    const int wo0  = (wave     ) * 256 + ((lane * 4) ^ xors);
    const int wo1  = (wave + 16) * 256 + ((lane * 4) ^ xors);
    const int wo2  = (wave + 32) * 256 + ((lane * 4) ^ xors);

    auto cw = [&](char* buf, int g, int2 a, int2 b, int2 c) {
        float s0 = sc[(wave     ) * 32 + g];
        float s1 = sc[(wave + 16) * 32 + g];
        float s2 = sc[(wave + 32) * 32 + g];
        h16x2 h;
        h[0] = (_Float16)((float)a.x * s0); h[1] = (_Float16)((float)a.y * s0);
        *(h16x2*)(buf + wo0) = h;
        h[0] = (_Float16)((float)b.x * s1); h[1] = (_Float16)((float)b.y * s1);
        *(h16x2*)(buf + wo1) = h;
        h[0] = (_Float16)((float)c.x * s2); h[1] = (_Float16)((float)c.y * s2);
        *(h16x2*)(buf + wo2) = h;
    };

    // MFMA fragment addressing (16x16x32 f16); A/B share the k map -> HW order cancels
    const int arow = lane & 15;
    const int g16  = lane >> 4;
    const int xorv = (arow & 7) << 4;
    const size_t aidx0 = (size_t)(wave * 16 + arow) * KDIM + g16 * 8;

    auto load_a = [&](size_t idx) -> h16x8 {
        if constexpr (USE_F16X) {
            return *(const h16x8*)(xf16 + idx);
        } else {
            f32x4 u0 = *(const f32x4*)(xf32 + idx);
            f32x4 u1 = *(const f32x4*)(xf32 + idx + 4);
            h16x8 a;
            a[0] = (_Float16)u0[0]; a[1] = (_Float16)u0[1];
            a[2] = (_Float16)u0[2]; a[3] = (_Float16)u0[3];
            a[4] = (_Float16)u1[0]; a[5] = (_Float16)u1[1];
            a[6] = (_Float16)u1[2]; a[7] = (_Float16)u1[3];
            return a;
        }
    };

    f32x4 acc0 = {0.f, 0.f, 0.f, 0.f}, acc1 = acc0, acc2 = acc0;

    __syncthreads();   // sc visible (only scale loads outstanding; full drain once)

    // Prologue: W(0) staged now; W(1), W(2) held in the register pipeline.
    int2 q00 = wb0[0],   q01 = wb1[0],   q02 = wb2[0];
    int2 qa0 = wb0[64],  qa1 = wb1[64],  qa2 = wb2[64];
    int2 qb0 = wb0[128], qb1 = wb1[128], qb2 = wb2[128];
    cw(&wl[0][0], 0, q00, q01, q02);     // vmcnt wait covers q0* only
    asm volatile("s_waitcnt lgkmcnt(0)" ::: "memory");
    __builtin_amdgcn_s_barrier();        // buf0 ready; qa/qb stay in flight

    for (int t = 0; t < NT; ++t) {
        char* bufr = &wl[t & 1][0];
        char* bufw = &wl[(t + 1) & 1][0];

        // Issue A(t) FIRST, then W(t+3): the counted vmcnt wait for A leaves
        // all W loads outstanding (~2 iterations in flight, covers HBM latency).
        const size_t ab = aidx0 + (size_t)t * 128;
        h16x8 a0 = load_a(ab);
        h16x8 a1 = load_a(ab + 32);
        h16x8 a2 = load_a(ab + 64);
        h16x8 a3 = load_a(ab + 96);
        const int tn = (t + 3 < NT) ? (t + 3) * 64 : (NT - 1) * 64;
        int2 qn0 = wb0[tn], qn1 = wb1[tn], qn2 = wb2[tn];

        #pragma unroll
        for (int kk = 0; kk < 4; ++kk) {
            const int bo = (kk * 64 + g16 * 16) ^ xorv;
            h16x8 b0 = *(const h16x8*)(bufr + (     arow) * 256 + bo);
            h16x8 b1 = *(const h16x8*)(bufr + (16 + arow) * 256 + bo);
            h16x8 b2 = *(const h16x8*)(bufr + (32 + arow) * 256 + bo);
            h16x8 a  = (kk == 0) ? a0 : (kk == 1) ? a1 : (kk == 2) ? a2 : a3;
            acc0 = __builtin_amdgcn_mfma_f32_16x16x32_f16(a, b0, acc0, 0, 0, 0);
            acc1 = __builtin_amdgcn_mfma_f32_16x16x32_f16(a, b1, acc1, 0, 0, 0);
            acc2 = __builtin_amdgcn_mfma_f32_16x16x32_f16(a, b2, acc2, 0, 0, 0);
        }

        if (t + 1 < NT) {
            cw(bufw, t + 1, qa0, qa1, qa2);   // W(t+1), loaded 2 iters ago
            // Counted barrier: drain LDS only; global loads stay in flight.
            asm volatile("s_waitcnt lgkmcnt(0)" ::: "memory");
            __builtin_amdgcn_s_barrier();
        }
        qa0 = qb0; qa1 = qb1; qa2 = qb2;
        qb0 = qn0; qb1 = qn1; qb2 = qn2;
    }

    // Epilogue: D row = 4*(lane>>4)+r, col = lane&15 (m89-verified)
    float bv0 = bias[n0 +      arow];
    float bv1 = bias[n0 + 16 + arow];
    float bv2 = bias[n0 + 32 + arow];
    #pragma unroll
    for (int r = 0; r < 4; ++r) {
        int m = wave * 16 + g16 * 4 + r;
        float* op = out + (size_t)m * NDIM + n0 + arow;
        op[0]  = acc0[r] + bv0;
        op[16] = acc1[r] + bv1;
        op[32] = acc2[r] + bv2;
    }
}

extern "C" void kernel_launch(void* const* d_in, const int* in_sizes, int n_in,
                              void* d_out, int out_size, void* d_ws, size_t ws_size,
                              hipStream_t stream) {
    const float* x      = (const float*)d_in[0];
    const float* scales = (const float*)d_in[1];
    const float* bias   = (const float*)d_in[2];
    const int*   wq     = (const int*)d_in[3];
    float*       out    = (float*)d_out;

    const size_t xf_bytes = (size_t)MDIM * KDIM * sizeof(_Float16);  // 2 MB
    if (ws_size >= xf_bytes) {
        _Float16* xf = (_Float16*)d_ws;
        cvt_x_kernel<<<dim3(MDIM * KDIM / 1024), dim3(256), 0, stream>>>(x, xf);
        qlin_kernel<1><<<dim3(NDIM / N_TILE), dim3(1024), 0, stream>>>(x, xf, scales, bias, wq, out);
    } else {
        qlin_kernel<0><<<dim3(NDIM / N_TILE), dim3(1024), 0, stream>>>(x, nullptr, scales, bias, wq, out);
    }
}